// Round 15
// baseline (43.623 us; speedup 1.0000x reference)
//
#include <hip/hip_runtime.h>
#include <math.h>

namespace {
constexpr int KB    = 16;        // spline bins
constexpr int OUTP  = 3*KB + 1;  // 49
constexpr int CDIM  = 64;
constexpr int HDIM  = 256;
constexpr int NCOL  = 1024;
constexpr int NROW  = 4096;
constexpr float BOUNDF = 5.0f;
constexpr float MBW_ = 0.001f;
constexpr float MBH_ = 0.001f;
constexpr float MD_  = 0.001f;
constexpr int PSTR  = 51;   // 17 cumw | 17 cumh | 17 deriv
constexpr int MROWS = 8;    // rows per MLP block (half M-tile -> 2 blocks/CU)
constexpr int HSTR  = 260;  // padded LDS stride (uints)
// tiled weight-plane sizes (elems): [tiles][chunks][kg:4][mrow:16][j:8]
constexpr int W1E = 16*2*512;   // 16384
constexpr int W2E = 16*8*512;   // 65536
constexpr int W3E = 4*8*512;    // 16384
}

typedef __attribute__((ext_vector_type(8))) short bf16x8;   // 8 bf16 (4 VGPR)
typedef __attribute__((ext_vector_type(4))) float f32x4;    // MFMA acc

__device__ __forceinline__ unsigned short f32_to_bf16_rne(float v) {
    unsigned u = __float_as_uint(v);
    return (unsigned short)((u + 0x7FFFu + ((u >> 16) & 1u)) >> 16);
}
__device__ __forceinline__ float bf16_to_f32(unsigned short h) {
    return __uint_as_float(((unsigned)h) << 16);
}
__device__ __forceinline__ void split_bf16(float v, unsigned short& hi, unsigned short& lo) {
    hi = f32_to_bf16_rne(v);
    lo = f32_to_bf16_rne(v - bf16_to_f32(hi));
}
__device__ __forceinline__ unsigned pack_split(float v) {
    unsigned short h, l; split_bf16(v, h, l);
    return (unsigned)h | ((unsigned)l << 16);
}

// tiled index for B-planes: from (k, col) -> [T][c][kg][mrow][j]
__device__ __forceinline__ int tiled_idx(int k, int col, int nchunk) {
    const int c = k >> 5, kg = (k >> 3) & 3, j = k & 7;
    const int T = col >> 4, mrow = col & 15;
    return ((T*nchunk + c) << 9) + (kg << 7) + (mrow << 3) + j;
}

// ---------------------------------------------------------------------------
// Prep (verbatim R13/R14): coalesced reads, scattered 2B stores, tiled layout.
// ---------------------------------------------------------------------------
__global__ __launch_bounds__(256) void prep_weights(
    const float* __restrict__ W1, const float* __restrict__ W2,
    const float* __restrict__ W3,
    unsigned short* __restrict__ w1hi, unsigned short* __restrict__ w1lo,
    unsigned short* __restrict__ w2hi, unsigned short* __restrict__ w2lo,
    unsigned short* __restrict__ w3hi, unsigned short* __restrict__ w3lo)
{
    const int t = blockIdx.x * 256 + threadIdx.x;   // 0..65535
    {   // W2
        const int k = t >> 8, col = t & 255;
        unsigned short h, l; split_bf16(W2[t], h, l);
        const int d = tiled_idx(k, col, 8);
        w2hi[d] = h; w2lo[d] = l;
    }
    if (t < W1E) {   // W1: [64 k][256 col]
        const int k = t >> 8, col = t & 255;
        unsigned short h, l; split_bf16(W1[t], h, l);
        const int d = tiled_idx(k, col, 2);
        w1hi[d] = h; w1lo[d] = l;
    }
    if (t < W3E) {   // W3 padded [256 k][64 col]
        const int k = t >> 6, col = t & 63;
        const float v = (col < OUTP) ? W3[(size_t)k*OUTP + col] : 0.f;
        unsigned short h, l; split_bf16(v, h, l);
        const int d = tiled_idx(k, col, 8);
        w3hi[d] = h; w3lo[d] = l;
    }
}

// ---------------------------------------------------------------------------
// MFMA MLP, 8 rows/block, 512 blocks x 8 waves -> 2 blocks/CU = 4 waves/SIMD
// (2x R14's occupancy; the clean latency-exposure test). M-tile rows 8-15
// are clamped-garbage and never stored. Fragment maps unchanged (pass since
// R10):  A: lane holds A[lane&15][(lane>>4)*8+j]
//        B: lane kg*16+mrow holds B[c*32+kg*8+j][T*16+mrow]
//        C: col = lane&15, row = (lane>>4)*4 + reg
// ---------------------------------------------------------------------------
__global__ __launch_bounds__(512, 4) void mlp_mfma_kernel(
    const float* __restrict__ cond,
    const float* __restrict__ b1, const float* __restrict__ b2,
    const float* __restrict__ b3,
    const unsigned short* __restrict__ w1hi, const unsigned short* __restrict__ w1lo,
    const unsigned short* __restrict__ w2hi, const unsigned short* __restrict__ w2lo,
    const unsigned short* __restrict__ w3hi, const unsigned short* __restrict__ w3lo,
    float* __restrict__ params)
{
    __shared__ unsigned h1c[MROWS][HSTR];   // 8.3 KB packed h1 (hi|lo)
    __shared__ unsigned h2c[MROWS][HSTR];   // 8.3 KB packed h2
    __shared__ float    p_s[MROWS][OUTP];
    __shared__ float    prm_s[MROWS][PSTR];

    const int tid  = threadIdx.x;
    const int lane = tid & 63;
    const int wid  = tid >> 6;        // 0..7
    const int mrow = lane & 15;
    const int arow = mrow & 7;        // clamped A-row (rows 8-15 duplicate 0-7)
    const int kg   = lane >> 4;
    const int row0 = blockIdx.x * MROWS;

    // ================= layer 1: h1 = relu(cond @ W1 + b1) ==================
    {
        f32x4 ahh[2], ahl[2], alh[2];
        #pragma unroll
        for (int t = 0; t < 2; ++t) { ahh[t] = (f32x4)0.f; ahl[t] = (f32x4)0.f; alh[t] = (f32x4)0.f; }

        #pragma unroll
        for (int c = 0; c < CDIM/32; ++c) {
            const float* ap = cond + (size_t)(row0 + arow)*CDIM + c*32 + kg*8;
            const float4 a0 = *(const float4*)ap;
            const float4 a1 = *(const float4*)(ap + 4);
            const float av[8] = {a0.x,a0.y,a0.z,a0.w,a1.x,a1.y,a1.z,a1.w};
            bf16x8 Ahi, Alo;
            #pragma unroll
            for (int j = 0; j < 8; ++j) {
                unsigned short h, l; split_bf16(av[j], h, l);
                Ahi[j] = (short)h; Alo[j] = (short)l;
            }
            #pragma unroll
            for (int t = 0; t < 2; ++t) {
                const int T = 2*wid + t;
                const size_t off = (size_t)(T*2 + c)*512 + lane*8;
                const bf16x8 Bhi = *(const bf16x8*)(w1hi + off);
                const bf16x8 Blo = *(const bf16x8*)(w1lo + off);
                ahh[t] = __builtin_amdgcn_mfma_f32_16x16x32_bf16(Ahi, Bhi, ahh[t], 0, 0, 0);
                ahl[t] = __builtin_amdgcn_mfma_f32_16x16x32_bf16(Ahi, Blo, ahl[t], 0, 0, 0);
                alh[t] = __builtin_amdgcn_mfma_f32_16x16x32_bf16(Alo, Bhi, alh[t], 0, 0, 0);
            }
        }
        if (kg < 2) {                 // D rows kg*4+r in 0..7 only
            #pragma unroll
            for (int t = 0; t < 2; ++t) {
                const int col = (2*wid + t)*16 + mrow;
                const float bb = b1[col];
                #pragma unroll
                for (int r = 0; r < 4; ++r) {
                    const float v = fmaxf(ahh[t][r] + ahl[t][r] + alh[t][r] + bb, 0.f);
                    h1c[kg*4 + r][col] = pack_split(v);
                }
            }
        }
    }
    __syncthreads();

    // ================= layer 2: h2 = relu(h1 @ W2 + b2) ==================
    {
        f32x4 ahh[2], ahl[2], alh[2];
        #pragma unroll
        for (int t = 0; t < 2; ++t) { ahh[t] = (f32x4)0.f; ahl[t] = (f32x4)0.f; alh[t] = (f32x4)0.f; }

        #pragma unroll 4
        for (int c = 0; c < HDIM/32; ++c) {
            const uint4 u0 = *(const uint4*)&h1c[arow][c*32 + kg*8];
            const uint4 u1 = *(const uint4*)&h1c[arow][c*32 + kg*8 + 4];
            const unsigned uu[8] = {u0.x,u0.y,u0.z,u0.w,u1.x,u1.y,u1.z,u1.w};
            bf16x8 Ahi, Alo;
            #pragma unroll
            for (int j = 0; j < 8; ++j) {
                Ahi[j] = (short)(uu[j] & 0xFFFFu);
                Alo[j] = (short)(uu[j] >> 16);
            }
            #pragma unroll
            for (int t = 0; t < 2; ++t) {
                const int T = 2*wid + t;
                const size_t off = (size_t)(T*8 + c)*512 + lane*8;
                const bf16x8 Bhi = *(const bf16x8*)(w2hi + off);
                const bf16x8 Blo = *(const bf16x8*)(w2lo + off);
                ahh[t] = __builtin_amdgcn_mfma_f32_16x16x32_bf16(Ahi, Bhi, ahh[t], 0, 0, 0);
                ahl[t] = __builtin_amdgcn_mfma_f32_16x16x32_bf16(Ahi, Blo, ahl[t], 0, 0, 0);
                alh[t] = __builtin_amdgcn_mfma_f32_16x16x32_bf16(Alo, Bhi, alh[t], 0, 0, 0);
            }
        }
        if (kg < 2) {
            #pragma unroll
            for (int t = 0; t < 2; ++t) {
                const int col = (2*wid + t)*16 + mrow;
                const float bb = b2[col];
                #pragma unroll
                for (int r = 0; r < 4; ++r) {
                    const float v = fmaxf(ahh[t][r] + ahl[t][r] + alh[t][r] + bb, 0.f);
                    h2c[kg*4 + r][col] = pack_split(v);
                }
            }
        }
    }
    __syncthreads();

    // ================= layer 3: p = h2 @ W3 + b3 (waves 0-3) ===============
    if (wid < 4) {
        f32x4 ahh = (f32x4)0.f, ahl = (f32x4)0.f, alh = (f32x4)0.f;
        #pragma unroll 4
        for (int c = 0; c < HDIM/32; ++c) {
            const uint4 u0 = *(const uint4*)&h2c[arow][c*32 + kg*8];
            const uint4 u1 = *(const uint4*)&h2c[arow][c*32 + kg*8 + 4];
            const unsigned uu[8] = {u0.x,u0.y,u0.z,u0.w,u1.x,u1.y,u1.z,u1.w};
            bf16x8 Ahi, Alo;
            #pragma unroll
            for (int j = 0; j < 8; ++j) {
                Ahi[j] = (short)(uu[j] & 0xFFFFu);
                Alo[j] = (short)(uu[j] >> 16);
            }
            const size_t off = (size_t)(wid*8 + c)*512 + lane*8;
            const bf16x8 Bhi = *(const bf16x8*)(w3hi + off);
            const bf16x8 Blo = *(const bf16x8*)(w3lo + off);
            ahh = __builtin_amdgcn_mfma_f32_16x16x32_bf16(Ahi, Bhi, ahh, 0, 0, 0);
            ahl = __builtin_amdgcn_mfma_f32_16x16x32_bf16(Ahi, Blo, ahl, 0, 0, 0);
            alh = __builtin_amdgcn_mfma_f32_16x16x32_bf16(Alo, Bhi, alh, 0, 0, 0);
        }
        const int col = wid*16 + mrow;
        if (col < OUTP && kg < 2) {
            const float bb = b3[col];
            #pragma unroll
            for (int r = 0; r < 4; ++r)
                p_s[kg*4 + r][col] = ahh[r] + ahl[r] + alh[r] + bb;
        }
    }
    __syncthreads();

    // ---- softmax+cumsum / softplus -> prm_s (8 rows x 3 tasks)
    if (tid < MROWS*3) {
        const int r   = tid / 3;
        const int seg = tid - 3*r;
        if (seg < 2) {
            const int   off   = (seg == 0) ? 0 : KB;
            const int   cbase = (seg == 0) ? 0 : 17;
            const float mb    = (seg == 0) ? MBW_ : MBH_;
            float m = -1e30f;
            #pragma unroll
            for (int i = 0; i < KB; ++i) m = fmaxf(m, p_s[r][off+i]);
            float e[KB];
            float s = 0.f;
            #pragma unroll
            for (int i = 0; i < KB; ++i) { e[i] = __expf(p_s[r][off+i] - m); s += e[i]; }
            const float span = (2.f*BOUNDF - (float)KB*mb) / s;
            float c = -BOUNDF;
            prm_s[r][cbase] = c;
            #pragma unroll
            for (int i = 0; i < KB; ++i) {
                c += mb + span*e[i];
                prm_s[r][cbase + 1 + i] = c;
            }
        } else {
            #pragma unroll
            for (int i = 0; i < KB+1; ++i) {
                const float x  = p_s[r][2*KB + i];
                const float sp = (x > 20.f) ? x : __logf(1.f + __expf(x));
                prm_s[r][34 + i] = MD_ + sp;
            }
        }
    }
    __syncthreads();

    for (int i = tid; i < MROWS*PSTR; i += 512)
        params[(size_t)row0*PSTR + i] = (&prm_s[0][0])[i];
}

// ---------------------------------------------------------------------------
// Spline application (verbatim R5/R13/R14 best): 4096 blocks, packed 32B bin
// records, single fast log.
// ---------------------------------------------------------------------------
__global__ __launch_bounds__(256) void spline_kernel(
    const float* __restrict__ y,
    const float* __restrict__ params,
    float* __restrict__ out,
    float* __restrict__ logdet)
{
    __shared__ float prm[PSTR];
    __shared__ float rec[KB][8];
    __shared__ float scan_s[KB];

    const int b   = blockIdx.x;
    const int tid = threadIdx.x;
    if (tid < PSTR) prm[tid] = params[(size_t)b*PSTR + tid];
    __syncthreads();
    if (tid < KB) {
        const int k = tid;
        rec[k][0] = prm[k];        rec[k][1] = prm[k+1];
        rec[k][2] = prm[17+k];     rec[k][3] = prm[17+k+1];
        rec[k][4] = prm[34+k];     rec[k][5] = prm[34+k+1];
        rec[k][6] = 0.f;           rec[k][7] = 0.f;
        scan_s[k] = prm[k+1];
    }
    __syncthreads();

    float cw[KB];
    #pragma unroll
    for (int q = 0; q < 4; ++q) {
        const float4 t4 = *(const float4*)&scan_s[4*q];
        cw[4*q+0] = t4.x; cw[4*q+1] = t4.y; cw[4*q+2] = t4.z; cw[4*q+3] = t4.w;
    }

    const size_t base = (size_t)b * NCOL + 4*tid;
    const float4 yv   = *(const float4*)(y + base);
    const float  yy[4] = {yv.x, yv.y, yv.z, yv.w};
    float ov[4], lv[4];

    #pragma unroll
    for (int i = 0; i < 4; ++i) {
        const float yi = yy[i];
        const bool outside = (yi < -BOUNDF) || (yi > BOUNDF);
        const float xc = fminf(fmaxf(yi, -BOUNDF), BOUNDF);
        int bin = 0;
        #pragma unroll
        for (int k = 0; k < KB; ++k) bin += (xc >= cw[k]) ? 1 : 0;
        bin = min(bin, KB-1);

        const float4 lo = *(const float4*)&rec[bin][0];
        const float2 hi = *(const float2*)&rec[bin][4];
        const float w  = lo.y - lo.x;
        const float hh = lo.w - lo.z;
        const float d0 = hi.x, d1 = hi.y;

        const float inv_w = __fdividef(1.f, w);
        const float delta = hh * inv_w;
        const float theta = (xc - lo.x) * inv_w;
        const float omt   = 1.f - theta;
        const float tt    = theta * theta;
        const float tomt  = theta * omt;
        const float num   = hh * (delta*tt + d0*tomt);
        const float den   = delta + (d0 + d1 - 2.f*delta)*tomt;
        const float o     = lo.z + __fdividef(num, den);
        const float der_num = fmaxf(delta*delta*(d1*tt + 2.f*delta*tomt + d0*omt*omt), 1e-12f);
        const float der_den = fmaxf(den*den, 1e-12f);
        const float ld      = __logf(__fdividef(der_num, der_den));

        ov[i] = outside ? yi : o;
        lv[i] = outside ? 0.f : ld;
    }

    *(float4*)(out + base)    = make_float4(ov[0], ov[1], ov[2], ov[3]);
    *(float4*)(logdet + base) = make_float4(lv[0], lv[1], lv[2], lv[3]);
}

extern "C" void kernel_launch(void* const* d_in, const int* in_sizes, int n_in,
                              void* d_out, int out_size, void* d_ws, size_t ws_size,
                              hipStream_t stream) {
    const float* cond = (const float*)d_in[0];
    const float* y    = (const float*)d_in[1];
    const float* W1   = (const float*)d_in[2];
    const float* b1   = (const float*)d_in[3];
    const float* W2   = (const float*)d_in[4];
    const float* b2   = (const float*)d_in[5];
    const float* W3   = (const float*)d_in[6];
    const float* b3   = (const float*)d_in[7];

    float* out    = (float*)d_out;
    float* logdet = out + (size_t)NROW * NCOL;

    // d_ws: params @0 (836 KB); tiled bf16 hi/lo weight planes @1MB.
    float* params = (float*)d_ws;
    unsigned short* w1hi = (unsigned short*)((char*)d_ws + (1 << 20));
    unsigned short* w1lo = w1hi + W1E;
    unsigned short* w2hi = w1lo + W1E;
    unsigned short* w2lo = w2hi + W2E;
    unsigned short* w3hi = w2lo + W2E;
    unsigned short* w3lo = w3hi + W3E;

    prep_weights<<<256, 256, 0, stream>>>(W1, W2, W3, w1hi, w1lo, w2hi, w2lo, w3hi, w3lo);
    mlp_mfma_kernel<<<NROW/MROWS, 512, 0, stream>>>(cond, b1, b2, b3,
                                                    w1hi, w1lo, w2hi, w2lo, w3hi, w3lo,
                                                    params);
    spline_kernel<<<NROW, 256, 0, stream>>>(y, params, out, logdet);
}

// Round 16
// 36.836 us; speedup vs baseline: 1.1843x; 1.1843x over previous
//
#include <hip/hip_runtime.h>
#include <math.h>

namespace {
constexpr int KB    = 16;        // spline bins
constexpr int OUTP  = 3*KB + 1;  // 49
constexpr int CDIM  = 64;
constexpr int HDIM  = 256;
constexpr int NCOL  = 1024;
constexpr int NROW  = 4096;
constexpr float BOUNDF = 5.0f;
constexpr float MBW_ = 0.001f;
constexpr float MBH_ = 0.001f;
constexpr float MD_  = 0.001f;
constexpr int PSTR  = 51;   // 17 cumw | 17 cumh | 17 deriv
constexpr int MROWS = 16;   // rows per MLP block (best-measured: R14)
constexpr int HSTR  = 260;  // padded LDS stride (uints)
// tiled weight-plane sizes (elems): [tiles][chunks][kg:4][mrow:16][j:8]
constexpr int W1E = 16*2*512;   // 16384
constexpr int W2E = 16*8*512;   // 65536
constexpr int W3E = 4*8*512;    // 16384
}

typedef __attribute__((ext_vector_type(8))) short bf16x8;   // 8 bf16 (4 VGPR)
typedef __attribute__((ext_vector_type(4))) float f32x4;    // MFMA acc

__device__ __forceinline__ unsigned short f32_to_bf16_rne(float v) {
    unsigned u = __float_as_uint(v);
    return (unsigned short)((u + 0x7FFFu + ((u >> 16) & 1u)) >> 16);
}
__device__ __forceinline__ float bf16_to_f32(unsigned short h) {
    return __uint_as_float(((unsigned)h) << 16);
}
__device__ __forceinline__ void split_bf16(float v, unsigned short& hi, unsigned short& lo) {
    hi = f32_to_bf16_rne(v);
    lo = f32_to_bf16_rne(v - bf16_to_f32(hi));
}
__device__ __forceinline__ unsigned pack_split(float v) {
    unsigned short h, l; split_bf16(v, h, l);
    return (unsigned)h | ((unsigned)l << 16);
}

// tiled index for B-planes: from (k, col) -> [T][c][kg][mrow][j]
__device__ __forceinline__ int tiled_idx(int k, int col, int nchunk) {
    const int c = k >> 5, kg = (k >> 3) & 3, j = k & 7;
    const int T = col >> 4, mrow = col & 15;
    return ((T*nchunk + c) << 9) + (kg << 7) + (mrow << 3) + j;
}

// ---------------------------------------------------------------------------
// Prep (verbatim R13/R14): coalesced reads, scattered 2B stores, tiled layout.
// ---------------------------------------------------------------------------
__global__ __launch_bounds__(256) void prep_weights(
    const float* __restrict__ W1, const float* __restrict__ W2,
    const float* __restrict__ W3,
    unsigned short* __restrict__ w1hi, unsigned short* __restrict__ w1lo,
    unsigned short* __restrict__ w2hi, unsigned short* __restrict__ w2lo,
    unsigned short* __restrict__ w3hi, unsigned short* __restrict__ w3lo)
{
    const int t = blockIdx.x * 256 + threadIdx.x;   // 0..65535
    {   // W2
        const int k = t >> 8, col = t & 255;
        unsigned short h, l; split_bf16(W2[t], h, l);
        const int d = tiled_idx(k, col, 8);
        w2hi[d] = h; w2lo[d] = l;
    }
    if (t < W1E) {   // W1: [64 k][256 col]
        const int k = t >> 8, col = t & 255;
        unsigned short h, l; split_bf16(W1[t], h, l);
        const int d = tiled_idx(k, col, 2);
        w1hi[d] = h; w1lo[d] = l;
    }
    if (t < W3E) {   // W3 padded [256 k][64 col]
        const int k = t >> 6, col = t & 63;
        const float v = (col < OUTP) ? W3[(size_t)k*OUTP + col] : 0.f;
        unsigned short h, l; split_bf16(v, h, l);
        const int d = tiled_idx(k, col, 8);
        w3hi[d] = h; w3lo[d] = l;
    }
}

// ---------------------------------------------------------------------------
// MFMA MLP (verbatim R14 best): 8 waves, 16 rows/block, 3-way independent
// accumulator chains, fully unrolled K-loops. Fragment maps (pass since R10):
//   A: lane holds A[lane&15][(lane>>4)*8 + j]
//   B: lane kg*16+mrow holds B[c*32+kg*8+j][T*16+mrow]  (wave-tiled planes)
//   C: col = lane&15, row = (lane>>4)*4 + reg
// ---------------------------------------------------------------------------
__global__ __launch_bounds__(512) void mlp_mfma_kernel(
    const float* __restrict__ cond,
    const float* __restrict__ b1, const float* __restrict__ b2,
    const float* __restrict__ b3,
    const unsigned short* __restrict__ w1hi, const unsigned short* __restrict__ w1lo,
    const unsigned short* __restrict__ w2hi, const unsigned short* __restrict__ w2lo,
    const unsigned short* __restrict__ w3hi, const unsigned short* __restrict__ w3lo,
    float* __restrict__ params)
{
    __shared__ unsigned h1c[MROWS][HSTR];   // 16.6 KB packed h1 (hi|lo)
    __shared__ unsigned h2c[MROWS][HSTR];   // 16.6 KB packed h2
    __shared__ float    p_s[MROWS][OUTP];
    __shared__ float    prm_s[MROWS][PSTR];

    const int tid  = threadIdx.x;
    const int lane = tid & 63;
    const int wid  = tid >> 6;        // 0..7
    const int mrow = lane & 15;
    const int kg   = lane >> 4;
    const int row0 = blockIdx.x * MROWS;

    // ================= layer 1: h1 = relu(cond @ W1 + b1) ==================
    {
        f32x4 ahh[2], ahl[2], alh[2];
        #pragma unroll
        for (int t = 0; t < 2; ++t) { ahh[t] = (f32x4)0.f; ahl[t] = (f32x4)0.f; alh[t] = (f32x4)0.f; }

        #pragma unroll
        for (int c = 0; c < CDIM/32; ++c) {
            const float* ap = cond + (size_t)(row0 + mrow)*CDIM + c*32 + kg*8;
            const float4 a0 = *(const float4*)ap;
            const float4 a1 = *(const float4*)(ap + 4);
            const float av[8] = {a0.x,a0.y,a0.z,a0.w,a1.x,a1.y,a1.z,a1.w};
            bf16x8 Ahi, Alo;
            #pragma unroll
            for (int j = 0; j < 8; ++j) {
                unsigned short h, l; split_bf16(av[j], h, l);
                Ahi[j] = (short)h; Alo[j] = (short)l;
            }
            #pragma unroll
            for (int t = 0; t < 2; ++t) {
                const int T = 2*wid + t;
                const size_t off = (size_t)(T*2 + c)*512 + lane*8;
                const bf16x8 Bhi = *(const bf16x8*)(w1hi + off);
                const bf16x8 Blo = *(const bf16x8*)(w1lo + off);
                ahh[t] = __builtin_amdgcn_mfma_f32_16x16x32_bf16(Ahi, Bhi, ahh[t], 0, 0, 0);
                ahl[t] = __builtin_amdgcn_mfma_f32_16x16x32_bf16(Ahi, Blo, ahl[t], 0, 0, 0);
                alh[t] = __builtin_amdgcn_mfma_f32_16x16x32_bf16(Alo, Bhi, alh[t], 0, 0, 0);
            }
        }
        #pragma unroll
        for (int t = 0; t < 2; ++t) {
            const int col = (2*wid + t)*16 + mrow;
            const float bb = b1[col];
            #pragma unroll
            for (int r = 0; r < 4; ++r) {
                const float v = fmaxf(ahh[t][r] + ahl[t][r] + alh[t][r] + bb, 0.f);
                h1c[kg*4 + r][col] = pack_split(v);
            }
        }
    }
    __syncthreads();

    // ================= layer 2: h2 = relu(h1 @ W2 + b2) ==================
    {
        f32x4 ahh[2], ahl[2], alh[2];
        #pragma unroll
        for (int t = 0; t < 2; ++t) { ahh[t] = (f32x4)0.f; ahl[t] = (f32x4)0.f; alh[t] = (f32x4)0.f; }

        #pragma unroll
        for (int c = 0; c < HDIM/32; ++c) {               // fully unrolled (8)
            const uint4 u0 = *(const uint4*)&h1c[mrow][c*32 + kg*8];
            const uint4 u1 = *(const uint4*)&h1c[mrow][c*32 + kg*8 + 4];
            const unsigned uu[8] = {u0.x,u0.y,u0.z,u0.w,u1.x,u1.y,u1.z,u1.w};
            bf16x8 Ahi, Alo;
            #pragma unroll
            for (int j = 0; j < 8; ++j) {
                Ahi[j] = (short)(uu[j] & 0xFFFFu);
                Alo[j] = (short)(uu[j] >> 16);
            }
            #pragma unroll
            for (int t = 0; t < 2; ++t) {
                const int T = 2*wid + t;
                const size_t off = (size_t)(T*8 + c)*512 + lane*8;
                const bf16x8 Bhi = *(const bf16x8*)(w2hi + off);
                const bf16x8 Blo = *(const bf16x8*)(w2lo + off);
                ahh[t] = __builtin_amdgcn_mfma_f32_16x16x32_bf16(Ahi, Bhi, ahh[t], 0, 0, 0);
                ahl[t] = __builtin_amdgcn_mfma_f32_16x16x32_bf16(Ahi, Blo, ahl[t], 0, 0, 0);
                alh[t] = __builtin_amdgcn_mfma_f32_16x16x32_bf16(Alo, Bhi, alh[t], 0, 0, 0);
            }
        }
        #pragma unroll
        for (int t = 0; t < 2; ++t) {
            const int col = (2*wid + t)*16 + mrow;
            const float bb = b2[col];
            #pragma unroll
            for (int r = 0; r < 4; ++r) {
                const float v = fmaxf(ahh[t][r] + ahl[t][r] + alh[t][r] + bb, 0.f);
                h2c[kg*4 + r][col] = pack_split(v);
            }
        }
    }
    __syncthreads();

    // ================= layer 3: p = h2 @ W3 + b3 (waves 0-3) ===============
    if (wid < 4) {
        f32x4 ahh = (f32x4)0.f, ahl = (f32x4)0.f, alh = (f32x4)0.f;
        #pragma unroll
        for (int c = 0; c < HDIM/32; ++c) {               // fully unrolled (8)
            const uint4 u0 = *(const uint4*)&h2c[mrow][c*32 + kg*8];
            const uint4 u1 = *(const uint4*)&h2c[mrow][c*32 + kg*8 + 4];
            const unsigned uu[8] = {u0.x,u0.y,u0.z,u0.w,u1.x,u1.y,u1.z,u1.w};
            bf16x8 Ahi, Alo;
            #pragma unroll
            for (int j = 0; j < 8; ++j) {
                Ahi[j] = (short)(uu[j] & 0xFFFFu);
                Alo[j] = (short)(uu[j] >> 16);
            }
            const size_t off = (size_t)(wid*8 + c)*512 + lane*8;
            const bf16x8 Bhi = *(const bf16x8*)(w3hi + off);
            const bf16x8 Blo = *(const bf16x8*)(w3lo + off);
            ahh = __builtin_amdgcn_mfma_f32_16x16x32_bf16(Ahi, Bhi, ahh, 0, 0, 0);
            ahl = __builtin_amdgcn_mfma_f32_16x16x32_bf16(Ahi, Blo, ahl, 0, 0, 0);
            alh = __builtin_amdgcn_mfma_f32_16x16x32_bf16(Alo, Bhi, alh, 0, 0, 0);
        }
        const int col = wid*16 + mrow;
        if (col < OUTP) {
            const float bb = b3[col];
            #pragma unroll
            for (int r = 0; r < 4; ++r)
                p_s[kg*4 + r][col] = ahh[r] + ahl[r] + alh[r] + bb;
        }
    }
    __syncthreads();

    // ---- softmax+cumsum / softplus -> prm_s
    if (tid < MROWS*3) {
        const int r   = tid / 3;
        const int seg = tid - 3*r;
        if (seg < 2) {
            const int   off   = (seg == 0) ? 0 : KB;
            const int   cbase = (seg == 0) ? 0 : 17;
            const float mb    = (seg == 0) ? MBW_ : MBH_;
            float m = -1e30f;
            #pragma unroll
            for (int i = 0; i < KB; ++i) m = fmaxf(m, p_s[r][off+i]);
            float e[KB];
            float s = 0.f;
            #pragma unroll
            for (int i = 0; i < KB; ++i) { e[i] = __expf(p_s[r][off+i] - m); s += e[i]; }
            const float span = (2.f*BOUNDF - (float)KB*mb) / s;
            float c = -BOUNDF;
            prm_s[r][cbase] = c;
            #pragma unroll
            for (int i = 0; i < KB; ++i) {
                c += mb + span*e[i];
                prm_s[r][cbase + 1 + i] = c;
            }
        } else {
            #pragma unroll
            for (int i = 0; i < KB+1; ++i) {
                const float x  = p_s[r][2*KB + i];
                const float sp = (x > 20.f) ? x : __logf(1.f + __expf(x));
                prm_s[r][34 + i] = MD_ + sp;
            }
        }
    }
    __syncthreads();

    for (int i = tid; i < MROWS*PSTR; i += 512)
        params[(size_t)row0*PSTR + i] = (&prm_s[0][0])[i];
}

// ---------------------------------------------------------------------------
// Spline application (verbatim R5/R13/R14 best): 4096 blocks, packed 32B bin
// records, single fast log.
// ---------------------------------------------------------------------------
__global__ __launch_bounds__(256) void spline_kernel(
    const float* __restrict__ y,
    const float* __restrict__ params,
    float* __restrict__ out,
    float* __restrict__ logdet)
{
    __shared__ float prm[PSTR];
    __shared__ float rec[KB][8];
    __shared__ float scan_s[KB];

    const int b   = blockIdx.x;
    const int tid = threadIdx.x;
    if (tid < PSTR) prm[tid] = params[(size_t)b*PSTR + tid];
    __syncthreads();
    if (tid < KB) {
        const int k = tid;
        rec[k][0] = prm[k];        rec[k][1] = prm[k+1];
        rec[k][2] = prm[17+k];     rec[k][3] = prm[17+k+1];
        rec[k][4] = prm[34+k];     rec[k][5] = prm[34+k+1];
        rec[k][6] = 0.f;           rec[k][7] = 0.f;
        scan_s[k] = prm[k+1];
    }
    __syncthreads();

    float cw[KB];
    #pragma unroll
    for (int q = 0; q < 4; ++q) {
        const float4 t4 = *(const float4*)&scan_s[4*q];
        cw[4*q+0] = t4.x; cw[4*q+1] = t4.y; cw[4*q+2] = t4.z; cw[4*q+3] = t4.w;
    }

    const size_t base = (size_t)b * NCOL + 4*tid;
    const float4 yv   = *(const float4*)(y + base);
    const float  yy[4] = {yv.x, yv.y, yv.z, yv.w};
    float ov[4], lv[4];

    #pragma unroll
    for (int i = 0; i < 4; ++i) {
        const float yi = yy[i];
        const bool outside = (yi < -BOUNDF) || (yi > BOUNDF);
        const float xc = fminf(fmaxf(yi, -BOUNDF), BOUNDF);
        int bin = 0;
        #pragma unroll
        for (int k = 0; k < KB; ++k) bin += (xc >= cw[k]) ? 1 : 0;
        bin = min(bin, KB-1);

        const float4 lo = *(const float4*)&rec[bin][0];
        const float2 hi = *(const float2*)&rec[bin][4];
        const float w  = lo.y - lo.x;
        const float hh = lo.w - lo.z;
        const float d0 = hi.x, d1 = hi.y;

        const float inv_w = __fdividef(1.f, w);
        const float delta = hh * inv_w;
        const float theta = (xc - lo.x) * inv_w;
        const float omt   = 1.f - theta;
        const float tt    = theta * theta;
        const float tomt  = theta * omt;
        const float num   = hh * (delta*tt + d0*tomt);
        const float den   = delta + (d0 + d1 - 2.f*delta)*tomt;
        const float o     = lo.z + __fdividef(num, den);
        const float der_num = fmaxf(delta*delta*(d1*tt + 2.f*delta*tomt + d0*omt*omt), 1e-12f);
        const float der_den = fmaxf(den*den, 1e-12f);
        const float ld      = __logf(__fdividef(der_num, der_den));

        ov[i] = outside ? yi : o;
        lv[i] = outside ? 0.f : ld;
    }

    *(float4*)(out + base)    = make_float4(ov[0], ov[1], ov[2], ov[3]);
    *(float4*)(logdet + base) = make_float4(lv[0], lv[1], lv[2], lv[3]);
}

extern "C" void kernel_launch(void* const* d_in, const int* in_sizes, int n_in,
                              void* d_out, int out_size, void* d_ws, size_t ws_size,
                              hipStream_t stream) {
    const float* cond = (const float*)d_in[0];
    const float* y    = (const float*)d_in[1];
    const float* W1   = (const float*)d_in[2];
    const float* b1   = (const float*)d_in[3];
    const float* W2   = (const float*)d_in[4];
    const float* b2   = (const float*)d_in[5];
    const float* W3   = (const float*)d_in[6];
    const float* b3   = (const float*)d_in[7];

    float* out    = (float*)d_out;
    float* logdet = out + (size_t)NROW * NCOL;

    // d_ws: params @0 (836 KB); tiled bf16 hi/lo weight planes @1MB.
    float* params = (float*)d_ws;
    unsigned short* w1hi = (unsigned short*)((char*)d_ws + (1 << 20));
    unsigned short* w1lo = w1hi + W1E;
    unsigned short* w2hi = w1lo + W1E;
    unsigned short* w2lo = w2hi + W2E;
    unsigned short* w3hi = w2lo + W2E;
    unsigned short* w3lo = w3hi + W3E;

    prep_weights<<<256, 256, 0, stream>>>(W1, W2, W3, w1hi, w1lo, w2hi, w2lo, w3hi, w3lo);
    mlp_mfma_kernel<<<NROW/MROWS, 512, 0, stream>>>(cond, b1, b2, b3,
                                                    w1hi, w1lo, w2hi, w2lo, w3hi, w3lo,
                                                    params);
    spline_kernel<<<NROW, 256, 0, stream>>>(y, params, out, logdet);
}